// Round 11
// baseline (652.735 us; speedup 1.0000x reference)
//
#include <hip/hip_runtime.h>

// Problem constants
#define NS   4
#define CIN  64
#define COUT 4
#define HH   96
#define WW   96
#define HWSZ 9216
#define DS   5
#define KD   1600
#define ITER 7

// Tight f16 image geometry (5 shift buffers, 96 f16 per row)
#define TROWB 192                   // bytes per row (96 f16)
#define TCHB  (96*TROWB)            // per-channel bytes (18432)
#define TIMGB ((size_t)64*TCHB)     // per-sample bytes
#define TSB   ((size_t)256*TCHB)    // per-shift-buffer bytes
#define CORR_RS 84                  // corr row stride in floats

#define SKC  12                     // kc chunks (8 B-rows each)
#define RB   8

// LDS band geometry (corr path): 24 row-slots
#define CSTR  104                   // channel stride bytes (26 dwords -> 2-way banks, free)
#define SLOTB (64*CSTR)             // 6656; 24*6656 = 159744

// xty LDS geometry: A = 12 slots x 64ch x 104B (79872); B at 79872: 8 slots x 32col x 104B
#define XAOFF 0
#define XBOFF 79872
#define XBSLOT (32*CSTR)            // 3328

typedef _Float16 f16_t;
typedef _Float16 f16x8_t __attribute__((ext_vector_type(8)));
typedef float    f32x16_t __attribute__((ext_vector_type(16)));

static __device__ __forceinline__ float4 f4add(float4 a, float4 b) {
  return make_float4(a.x + b.x, a.y + b.y, a.z + b.z, a.w + b.w);
}
static __device__ __forceinline__ float4 f4sub(float4 a, float4 b) {
  return make_float4(a.x - b.x, a.y - b.y, a.z - b.z, a.w - b.w);
}
static __device__ __forceinline__ float4 f4mul(float4 a, float4 b) {
  return make_float4(a.x * b.x, a.y * b.y, a.z * b.z, a.w * b.w);
}
static __device__ __forceinline__ float4 f4div(float4 a, float4 b) {
  return make_float4(a.x / b.x, a.y / b.y, a.z / b.z, a.w / b.w);
}
static __device__ __forceinline__ float4 f4fma(float4 a, float4 b, float4 c) {
  return make_float4(fmaf(a.x, b.x, c.x), fmaf(a.y, b.y, c.y),
                     fmaf(a.z, b.z, c.z), fmaf(a.w, b.w, c.w));
}
static __device__ __forceinline__ float f4sel(float4 v, int c) {
  return c == 0 ? v.x : c == 1 ? v.y : c == 2 ? v.z : v.w;
}
static __device__ __forceinline__ unsigned int packh2(float a, float b) {
  f16_t h0 = (f16_t)a, h1 = (f16_t)b;
  return (unsigned int)__builtin_bit_cast(unsigned short, h0)
       | ((unsigned int)__builtin_bit_cast(unsigned short, h1) << 16);
}

// ---------------- convert: x -> 5 shifted f16 images TS; y -> 5 shifted f16 images YS ----------------
// TS_s[cg][r][j] = x[cg][r][j+s] (0 outside).  YS_v[nb][r][j] = y[nb][r][j+2-v] (0 outside).
__global__ __launch_bounds__(256) void convert_kernel(const float* __restrict__ xs,
                                                      const float* __restrict__ ys,
                                                      unsigned int* __restrict__ TS32,
                                                      unsigned int* __restrict__ YS32) {
  const int PER = 256 * 96 * 48;             // 1,179,648 uints per x-shift buffer
  const int TSTOT = 5 * PER;                 // 5,898,240
  int idx = blockIdx.x * 256 + threadIdx.x;
  if (idx < TSTOT) {
    int s = idx / PER;
    int rr = idx - s * PER;
    int p = rr % 48; int t = rr / 48;
    int r = t % 96;  int cg = t / 96;
    const float* row = xs + (size_t)cg * HWSZ + r * 96;
    int j0 = 2 * p, j1 = j0 + 1;
    float f0 = (j0 + s < 96) ? row[j0 + s] : 0.f;
    float f1 = (j1 + s < 96) ? row[j1 + s] : 0.f;
    TS32[idx] = packh2(f0, f1);
  } else {
    int i2 = idx - TSTOT;
    if (i2 >= 5 * 16 * 96 * 48) return;      // 368,640
    int v  = i2 / 73728;                     // 16*96*48
    int r3 = i2 % 73728;
    int nb = r3 / 4608;                      // 96*48
    int r4 = r3 % 4608;
    int r = r4 / 48, p = r4 % 48;
    const float* row = ys + (size_t)nb * HWSZ + r * 96;
    int c0 = 2 * p + 2 - v, c1 = c0 + 1;
    float f0 = (c0 >= 0 && c0 < 96) ? row[c0] : 0.f;
    float f1 = (c1 >= 0 && c1 < 96) ? row[c1] : 0.f;
    YS32[i2] = packh2(f0, f1);
  }
}

// ---------------- merged partial kernel ----------------
// bid < 240: corr band (proven round-10 path).
// bid >= 240 (48 blocks): xty via MFMA: C[c][b*5+v] partial over B rows [r0,r0+8),
// A = TS_0 rows [r0-2,r0+10) with 5-deep u-ring; B = YS (y shifted by 2-v), 20 cols pad 32.
__global__ __launch_bounds__(256, 1) void partial_kernel(const unsigned short* __restrict__ TS,
                                                         const unsigned short* __restrict__ YS,
                                                         float* __restrict__ corrPart,
                                                         float* __restrict__ xtyPart) {
  __shared__ __align__(16) unsigned char lds[24 * SLOTB];   // 159744 B
  int bid = blockIdx.x;
  int tid = threadIdx.x, wid = tid >> 6, lane = tid & 63;
  int l5 = lane >> 5, l31 = lane & 31;

  if (bid < 240) {
    // ================= corr band (round-10 verbatim) =================
    int n = bid & 3;
    int rest = bid >> 2;
    int sv = rest % 5;
    int kc = rest / 5;
    int r0 = kc * RB;
    int mt = wid >> 1, nt = wid & 1;
    const char* Abase = (const char*)TS + (size_t)n * TIMGB;
    const char* Bbase = (const char*)TS + (size_t)sv * TSB + (size_t)n * TIMGB;
    f32x16_t acc[9] = {};

    for (int kh = 0; kh < 2; ++kh) {
      if (kh) __syncthreads();
      for (int bb = 0; bb < 3; ++bb) {
        uint4 tmp[12];
#pragma unroll
        for (int i = 0; i < 12; ++i) {
          int q = (bb * 12 + i) * 256 + tid;
          int slot = q / 384;
          int rem = q - slot * 384;
          int ch = rem / 6, sub = rem - ch * 6;
          bool isA = slot < 16;
          int row = isA ? (r0 - 4 + slot) : (r0 + slot - 16);
          uint4 v = make_uint4(0u, 0u, 0u, 0u);
          if (row >= 0 && row < 96) {
            const char* src = (isA ? Abase : Bbase)
                            + (size_t)ch * TCHB + (size_t)row * TROWB + kh * 96 + sub * 16;
            v = *(const uint4*)src;
          }
          tmp[i] = v;
        }
#pragma unroll
        for (int i = 0; i < 12; ++i) {
          int q = (bb * 12 + i) * 256 + tid;
          int slot = q / 384;
          int rem = q - slot * 384;
          int ch = rem / 6, sub = rem - ch * 6;
          char* dst = (char*)lds + slot * SLOTB + ch * CSTR + sub * 16;
          *(uint2*)dst = make_uint2(tmp[i].x, tmp[i].y);
          *(uint2*)(dst + 8) = make_uint2(tmp[i].z, tmp[i].w);
        }
      }
      __syncthreads();

      int ca = mt * 32 + l31, cb = nt * 32 + l31;
#pragma unroll
      for (int ktl = 0; ktl < 3; ++ktl) {
        int ko = ktl * 32 + l5 * 16;
        auto frag = [&](int slot, int ch) -> f16x8_t {
          const char* p = (const char*)lds + slot * SLOTB + ch * CSTR + ko;
          uint2 lo = *(const uint2*)p;
          uint2 hi = *(const uint2*)(p + 8);
          uint4 u = make_uint4(lo.x, lo.y, hi.x, hi.y);
          return __builtin_bit_cast(f16x8_t, u);
        };
        f16x8_t ring[9];
#pragma unroll
        for (int t = 0; t < 9; ++t) ring[t] = frag(t, ca);
#pragma unroll
        for (int r = 0; r < 8; ++r) {
          f16x8_t b = frag(16 + r, cb);
#pragma unroll
          for (int du = 0; du < 9; ++du) {
            acc[du] = __builtin_amdgcn_mfma_f32_32x32x16_f16(
                ring[(r + 8 - du) % 9], b, acc[du], 0, 0, 0);
          }
          if (r < 7) ring[r % 9] = frag(r + 9, ca);
        }
      }
    }
#pragma unroll
    for (int du = 0; du < 9; ++du) {
      float* outp = corrPart + (((size_t)(sv * 9 + du) * SKC + kc) * 4 + n) * 4096;
#pragma unroll
      for (int rg = 0; rg < 16; ++rg) {
        int m  = mt * 32 + (rg & 3) + 8 * (rg >> 2) + 4 * l5;
        int nn = nt * 32 + l31;
        outp[m * 64 + nn] = acc[du][rg];
      }
    }
    return;
  }

  // ================= xty MFMA =================
  int id = bid - 240;                 // 48 = 4n x 12kc
  int n = id & 3, kc = id >> 2;
  int r0 = kc * RB;
  int mt = wid & 1, rh = wid >> 1;
  const char* Ab = (const char*)TS + (size_t)n * TIMGB;   // x shift 0
  const char* Yb = (const char*)YS;
  f32x16_t acc[5] = {};

  for (int kh = 0; kh < 2; ++kh) {
    if (kh) __syncthreads();
    for (int bb = 0; bb < 2; ++bb) {
      uint4 tmp[12];
#pragma unroll
      for (int i = 0; i < 12; ++i) {
        int q = (bb * 12 + i) * 256 + tid;   // < 6144
        uint4 val = make_uint4(0u, 0u, 0u, 0u);
        if (q < 4608) {                      // A: 12 slots x 64ch x 6
          int slot = q / 384, rem = q % 384, ch = rem / 6, sub = rem % 6;
          int grow = r0 - 2 + slot;
          if (grow >= 0 && grow < 96)
            val = *(const uint4*)(Ab + (size_t)ch * TCHB + (size_t)grow * TROWB + kh * 96 + sub * 16);
        } else if (q < 5568) {               // B real: 8 slots x 20col x 6
          int qq = q - 4608;
          int j = qq / 120, rem = qq % 120, col = rem / 6, sub = rem % 6;
          int b = col / 5, v = col % 5;
          int grow = r0 + j;
          val = *(const uint4*)(Yb + ((size_t)(v * 16 + n * 4 + b) * 96 + grow) * 192 + kh * 96 + sub * 16);
        }                                    // 5568..6143: zero pad cols 20..31
        tmp[i] = val;
      }
#pragma unroll
      for (int i = 0; i < 12; ++i) {
        int q = (bb * 12 + i) * 256 + tid;
        char* dst;
        if (q < 4608) {
          int slot = q / 384, rem = q % 384, ch = rem / 6, sub = rem % 6;
          dst = (char*)lds + XAOFF + slot * SLOTB + ch * CSTR + sub * 16;
        } else {
          int j, col, sub;
          if (q < 5568) { int qq = q - 4608; j = qq / 120; int rem = qq % 120; col = rem / 6; sub = rem % 6; }
          else          { int q2 = q - 5568; j = q2 / 72;  int rem = q2 % 72;  col = 20 + rem / 6; sub = rem % 6; }
          dst = (char*)lds + XBOFF + j * XBSLOT + col * CSTR + sub * 16;
        }
        *(uint2*)dst = make_uint2(tmp[i].x, tmp[i].y);
        *(uint2*)(dst + 8) = make_uint2(tmp[i].z, tmp[i].w);
      }
    }
    __syncthreads();

    int ca = mt * 32 + l31;
#pragma unroll
    for (int ktl = 0; ktl < 3; ++ktl) {
      int ko = ktl * 32 + l5 * 16;
      auto fragA = [&](int slot) -> f16x8_t {
        const char* p = (const char*)lds + XAOFF + slot * SLOTB + ca * CSTR + ko;
        uint2 lo = *(const uint2*)p; uint2 hi = *(const uint2*)(p + 8);
        return __builtin_bit_cast(f16x8_t, make_uint4(lo.x, lo.y, hi.x, hi.y));
      };
      auto fragB = [&](int j) -> f16x8_t {
        const char* p = (const char*)lds + XBOFF + j * XBSLOT + l31 * CSTR + ko;
        uint2 lo = *(const uint2*)p; uint2 hi = *(const uint2*)(p + 8);
        return __builtin_bit_cast(f16x8_t, make_uint4(lo.x, lo.y, hi.x, hi.y));
      };
      int rbase = 4 * rh;
      f16x8_t ring[5];
#pragma unroll
      for (int t = 0; t < 5; ++t) ring[(rbase + t) % 5] = fragA(rbase + t);
#pragma unroll
      for (int rr = 0; rr < 4; ++rr) {
        int r = rbase + rr;
        f16x8_t b = fragB(r);
#pragma unroll
        for (int u = 0; u < 5; ++u)
          acc[u] = __builtin_amdgcn_mfma_f32_32x32x16_f16(ring[(r + u) % 5], b, acc[u], 0, 0, 0);
        if (rr < 3) ring[r % 5] = fragA(r + 5);
      }
    }
  }

  // cross-wave (rh) reduce via LDS scratch, then write xtyPart[n][kc][u][64][32]
  __syncthreads();
  float* scr = (float*)lds;
#pragma unroll
  for (int u = 0; u < 5; ++u)
#pragma unroll
    for (int rg = 0; rg < 16; ++rg) {
      int m = mt * 32 + (rg & 3) + 8 * (rg >> 2) + 4 * l5;
      scr[rh * 10240 + u * 2048 + m * 32 + l31] = acc[u][rg];
    }
  __syncthreads();
  float* outp = xtyPart + (size_t)(n * SKC + kc) * 5 * 2048;
  for (int e = tid; e < 10240; e += 256)
    outp[e] = scr[e] + scr[10240 + e];
}

// ---------------- fused: corr reduce (0..163) + P build (164..263) ----------------
__global__ __launch_bounds__(256) void reduce_kernel(const float* __restrict__ corrPart,
                                                     float* __restrict__ corrP,
                                                     const float* __restrict__ xtyPart,
                                                     const float* __restrict__ dd,
                                                     const float* __restrict__ alpha,
                                                     const float* __restrict__ reg,
                                                     float* __restrict__ P) {
  int bid0 = blockIdx.x;
  if (bid0 < 164) {
    int n = bid0 / 41, p = bid0 % 41;
    int du, dv;
    if (p < 36) { du = p % 9; dv = 5 + p / 9; }
    else        { du = p - 36; dv = 4; }
    int t = (p < 36) ? (9 + p) : (p - 36);
    int o1 = du * 9 + dv, o2 = (8 - du) * 9 + (8 - dv);
    bool mir = !(du == 4 && dv == 4);
    for (int e = threadIdx.x; e < 4096; e += 256) {
      float s = 0.f;
#pragma unroll
      for (int kc = 0; kc < SKC; ++kc)
        s += corrPart[(((size_t)t * SKC + kc) * 4 + n) * 4096 + e];
      int m = e >> 6, nn = e & 63;
      corrP[((size_t)(n * 64 + m) * 64 + nn) * CORR_RS + o1] = s;
      if (mir) corrP[((size_t)(n * 64 + nn) * 64 + m) * CORR_RS + o2] = s;
    }
    return;
  }
  // P build: idx = ((n*1600 + c*25+u*5+v)*4 + b)
  int idx = (bid0 - 164) * 256 + threadIdx.x;   // < 25600
  int b = idx & 3;
  int row = (idx >> 2) % KD;
  int n = idx / 6400;
  int c = row / 25;
  int uv = row % 25;
  int u = uv / 5, v = uv % 5;
  float s = 0.f;
#pragma unroll
  for (int kc = 0; kc < SKC; ++kc)
    s += xtyPart[((size_t)(n * SKC + kc) * 5 + u) * 2048 + c * 32 + b * 5 + v];
  float a = alpha[n] * reg[0] * ((float)(HH * WW) / (float)(DS * DS * CIN));
  float dvv = dd[((size_t)(n * COUT + b) * CIN + c) * 25 + uv];
  P[idx] = s + a * dvv;
}

// ---------------- fused CG iteration (proven) ----------------
static __device__ __forceinline__ void allreduce2_f4(float4& a, float4& b,
                                                     float4* redA, float4* redB, int tid) {
#pragma unroll
  for (int off = 1; off < 64; off <<= 1) {
    a.x += __shfl_xor(a.x, off); a.y += __shfl_xor(a.y, off);
    a.z += __shfl_xor(a.z, off); a.w += __shfl_xor(a.w, off);
    b.x += __shfl_xor(b.x, off); b.y += __shfl_xor(b.y, off);
    b.z += __shfl_xor(b.z, off); b.w += __shfl_xor(b.w, off);
  }
  int wid = tid >> 6;
  if ((tid & 63) == 0) { redA[wid] = a; redB[wid] = b; }
  __syncthreads();
  float4 sa = f4add(f4add(redA[0], redA[1]), f4add(redA[2], redA[3]));
  float4 sb = f4add(f4add(redB[0], redB[1]), f4add(redB[2], redB[3]));
  __syncthreads();
  a = sa; b = sb;
}

__global__ __launch_bounds__(256) void cg_iter_kernel(
    const float* __restrict__ corrP, const float* __restrict__ P,
    const float* __restrict__ Rin, float* __restrict__ Rout,
    const float* __restrict__ Win, float* __restrict__ Wout,
    const float* __restrict__ PFin, float* __restrict__ PFout,
    float* __restrict__ X,
    const float* __restrict__ ralpha, const float* __restrict__ rreg,
    int first) {
  __shared__ float4 pS[KD];
  __shared__ float4 redA[4], redB[4];
  __shared__ float redW[4][25][4];

  int b = blockIdx.x;
  int n = b >> 6, c1 = b & 63;
  int tid = threadIdx.x;

  const float4* Rin4 = (const float4*)Rin + (size_t)n * KD;
  const float4* Win4 = (const float4*)Win + (size_t)n * KD;
  const float4* PFin4 = (const float4*)PFin + (size_t)n * KD;
  const float4* P4 = (const float4*)P + (size_t)n * KD;
  float4* Rout4 = (float4*)Rout + (size_t)n * KD;
  float4* PFout4 = (float4*)PFout + (size_t)n * KD;
  float4* X4 = (float4*)X + (size_t)n * KD;

  const float4 zero4 = make_float4(0.f, 0.f, 0.f, 0.f);
  float4 rv[7], wv[7], pv[7];
#pragma unroll
  for (int t = 0; t < 7; ++t) {
    int idx = tid + 256 * t;
    bool ok = idx < KD;
    if (first) {
      rv[t] = ok ? P4[idx] : zero4;
      wv[t] = zero4; pv[t] = zero4;
    } else {
      rv[t] = ok ? Rin4[idx] : zero4;
      wv[t] = ok ? Win4[idx] : zero4;
      pv[t] = ok ? PFin4[idx] : zero4;
    }
  }
  float4 rho_prev = zero4, pAp = zero4;
#pragma unroll
  for (int t = 0; t < 7; ++t) {
    rho_prev = f4fma(rv[t], rv[t], rho_prev);
    pAp = f4fma(pv[t], wv[t], pAp);
  }
  allreduce2_f4(rho_prev, pAp, redA, redB, tid);

  float4 av = first ? zero4 : f4div(rho_prev, pAp);

  float4 rho_k = zero4;
#pragma unroll
  for (int t = 0; t < 7; ++t) {
    rv[t] = f4sub(rv[t], f4mul(av, wv[t]));
    rho_k = f4fma(rv[t], rv[t], rho_k);
  }
  int lo = c1 * 25;
#pragma unroll
  for (int t = 0; t < 7; ++t) {
    int idx = tid + 256 * t;
    if (idx >= lo && idx < lo + 25) {
      if (first) X4[idx] = zero4;
      else X4[idx] = f4fma(av, pv[t], X4[idx]);
    }
  }
  float4 dummy = zero4;
  allreduce2_f4(rho_k, dummy, redA, redB, tid);

  float4 bv = first ? zero4 : f4div(rho_k, rho_prev);

#pragma unroll
  for (int t = 0; t < 7; ++t) {
    int idx = tid + 256 * t;
    if (idx < KD) {
      float4 pnew = f4fma(bv, pv[t], rv[t]);
      pS[idx] = pnew;
      if (idx >= lo && idx < lo + 25) {
        PFout4[idx] = pnew;
        Rout4[idx] = rv[t];
      }
    }
  }
  __syncthreads();

  int c2 = tid >> 2, col = tid & 3;
  const float4* crow4 = (const float4*)(corrP + (((size_t)(n * 64 + c1)) * 64 + c2) * CORR_RS);
  float creg[81];
#pragma unroll
  for (int t4 = 0; t4 < 20; ++t4) *(float4*)&creg[4 * t4] = crow4[t4];
  creg[80] = ((const float*)crow4)[80];

  float a25[25];
#pragma unroll
  for (int i = 0; i < 25; ++i) a25[i] = 0.f;
  const float* pSf = (const float*)pS;
#pragma unroll
  for (int j = 0; j < 25; ++j) {
    float pvv = pSf[(c2 * 25 + j) * 4 + col];
#pragma unroll
    for (int i = 0; i < 25; ++i) {
      const int i1 = i / 5, i2 = i % 5, j1 = j / 5, j2 = j % 5;
      a25[i] += creg[(j1 - i1 + 4) * 9 + (j2 - i2 + 4)] * pvv;
    }
  }
#pragma unroll
  for (int i = 0; i < 25; ++i) {
    float v = a25[i];
    v += __shfl_xor(v, 4); v += __shfl_xor(v, 8);
    v += __shfl_xor(v, 16); v += __shfl_xor(v, 32);
    a25[i] = v;
  }
  int wid = tid >> 6;
  if ((tid & 63) < 4) {
#pragma unroll
    for (int i = 0; i < 25; ++i) redW[wid][i][col] = a25[i];
  }
  __syncthreads();
  if (tid < 100) {
    int i = tid >> 2, cc = tid & 3;
    float wval = redW[0][i][cc] + redW[1][i][cc] + redW[2][i][cc] + redW[3][i][cc];
    float aa = ralpha[n] * rreg[0] * ((float)(HH * WW) / (float)(DS * DS * CIN));
    int row = lo + i;
    wval = fmaf(aa, pSf[row * 4 + cc], wval);
    Wout[((size_t)n * KD + row) * 4 + cc] = wval;
  }
}

// ---------------- finalize ----------------
__global__ __launch_bounds__(256) void cg_final_kernel(
    const float* __restrict__ Rin, const float* __restrict__ Win,
    const float* __restrict__ PFin, const float* __restrict__ X,
    float* __restrict__ out) {
  __shared__ float4 redA[4], redB[4];
  int b = blockIdx.x;
  int n = b >> 6, c1 = b & 63;
  int tid = threadIdx.x;

  const float4* Rin4 = (const float4*)Rin + (size_t)n * KD;
  const float4* Win4 = (const float4*)Win + (size_t)n * KD;
  const float4* PFin4 = (const float4*)PFin + (size_t)n * KD;
  const float4 zero4 = make_float4(0.f, 0.f, 0.f, 0.f);

  float4 rho = zero4, pAp = zero4;
#pragma unroll
  for (int t = 0; t < 7; ++t) {
    int idx = tid + 256 * t;
    if (idx < KD) {
      float4 r = Rin4[idx], w = Win4[idx], p = PFin4[idx];
      rho = f4fma(r, r, rho);
      pAp = f4fma(p, w, pAp);
    }
  }
  allreduce2_f4(rho, pAp, redA, redB, tid);
  float4 av = f4div(rho, pAp);

  if (tid < 100) {
    int i = tid >> 2, cc = tid & 3;
    int row = c1 * 25 + i;
    float a_cc = f4sel(av, cc);
    float xv = X[((size_t)n * KD + row) * 4 + cc] + a_cc * PFin[((size_t)n * KD + row) * 4 + cc];
    out[((size_t)(n * 4 + cc) * 64 + c1) * 25 + i] = xv;
  }
}

extern "C" void kernel_launch(void* const* d_in, const int* in_sizes, int n_in,
                              void* d_out, int out_size, void* d_ws, size_t ws_size,
                              hipStream_t stream) {
  (void)in_sizes; (void)n_in; (void)out_size; (void)ws_size;
  const float* xs    = (const float*)d_in[0];   // [4,1,64,96,96]
  const float* dd    = (const float*)d_in[1];   // [4,4,64,5,5]
  const float* ys    = (const float*)d_in[2];   // [4,4,1,96,96]
  const float* alpha = (const float*)d_in[3];   // [4]
  const float* reg   = (const float*)d_in[4];   // [1]
  float* out = (float*)d_out;
  float* ws  = (float*)d_ws;

  const size_t TS_FLOATS = 5898240;                        // 5 x 256 x 96 x 48 uints
  const size_t YS_FLOATS = 368640;                         // 5 x 16 x 96 x 48 uints
  const size_t SZ_CPART = (size_t)45 * SKC * 4 * 4096;     // 8,847,360
  const size_t SZ_XPART = (size_t)4 * SKC * 5 * 2048;      // 491,520
  const size_t SZ_V = (size_t)NS * KD * COUT;              // 25,600

  unsigned short* TS = (unsigned short*)ws;                // dead after partial
  unsigned short* YS = (unsigned short*)(ws + TS_FLOATS);  // dead after partial
  float* corrP = ws;                                       // overlays dead TS
  float* corrPart = ws + TS_FLOATS + YS_FLOATS;
  float* xtyPart = corrPart + SZ_CPART;
  float* P   = xtyPart + SZ_XPART;
  float* X   = P + SZ_V;
  float* R0  = X + SZ_V;
  float* R1  = R0 + SZ_V;
  float* W0  = R1 + SZ_V;
  float* W1  = W0 + SZ_V;
  float* PF0 = W1 + SZ_V;
  float* PF1 = PF0 + SZ_V;
  float* Rb[2] = {R0, R1};
  float* Wb[2] = {W0, W1};
  float* Pb[2] = {PF0, PF1};

  convert_kernel<<<24480, 256, 0, stream>>>(xs, ys, (unsigned int*)TS, (unsigned int*)YS);
  partial_kernel<<<288, 256, 0, stream>>>(TS, YS, corrPart, xtyPart);
  reduce_kernel<<<264, 256, 0, stream>>>(corrPart, corrP, xtyPart, dd, alpha, reg, P);
  for (int k = 0; k < ITER; ++k) {
    cg_iter_kernel<<<NS * CIN, 256, 0, stream>>>(
        corrP, P,
        Rb[k & 1], Rb[(k + 1) & 1],
        Wb[k & 1], Wb[(k + 1) & 1],
        Pb[k & 1], Pb[(k + 1) & 1],
        X, alpha, reg, k == 0 ? 1 : 0);
  }
  cg_final_kernel<<<NS * CIN, 256, 0, stream>>>(Rb[ITER & 1], Wb[ITER & 1], Pb[ITER & 1], X, out);
}

// Round 12
// 139.529 us; speedup vs baseline: 4.6781x; 4.6781x over previous
//
#include <hip/hip_runtime.h>

// Problem constants
#define NS   4
#define CIN  64
#define COUT 4
#define HH   96
#define WW   96
#define HWSZ 9216
#define DS   5
#define KD   1600
#define ITER 7

// Tight f16 image geometry (5 shift buffers, 96 f16 per row)
#define TROWB 192                   // bytes per row (96 f16)
#define TCHB  (96*TROWB)            // per-channel bytes (18432)
#define TIMGB ((size_t)64*TCHB)     // per-sample bytes
#define TSB   ((size_t)256*TCHB)    // per-shift-buffer bytes
#define CORR_RS 84                  // corr row stride in floats

#define SKC  12                     // kc chunks (8 B-rows each)
#define RB   8

// LDS band geometry (corr path): 24 row-slots
#define CSTR  104                   // channel stride bytes (26 dwords -> 2-way banks, free)
#define SLOTB (64*CSTR)             // 6656; 24*6656 = 159744

// xty LDS geometry: A = 12 slots x 64ch x 104B (79872); B at 79872: 8 slots x 32col x 104B
#define XAOFF 0
#define XBOFF 79872
#define XBSLOT (32*CSTR)            // 3328

typedef _Float16 f16_t;
typedef _Float16 f16x8_t __attribute__((ext_vector_type(8)));
typedef float    f32x16_t __attribute__((ext_vector_type(16)));

static __device__ __forceinline__ float4 f4add(float4 a, float4 b) {
  return make_float4(a.x + b.x, a.y + b.y, a.z + b.z, a.w + b.w);
}
static __device__ __forceinline__ float4 f4sub(float4 a, float4 b) {
  return make_float4(a.x - b.x, a.y - b.y, a.z - b.z, a.w - b.w);
}
static __device__ __forceinline__ float4 f4mul(float4 a, float4 b) {
  return make_float4(a.x * b.x, a.y * b.y, a.z * b.z, a.w * b.w);
}
static __device__ __forceinline__ float4 f4div(float4 a, float4 b) {
  return make_float4(a.x / b.x, a.y / b.y, a.z / b.z, a.w / b.w);
}
static __device__ __forceinline__ float4 f4fma(float4 a, float4 b, float4 c) {
  return make_float4(fmaf(a.x, b.x, c.x), fmaf(a.y, b.y, c.y),
                     fmaf(a.z, b.z, c.z), fmaf(a.w, b.w, c.w));
}
static __device__ __forceinline__ float f4sel(float4 v, int c) {
  return c == 0 ? v.x : c == 1 ? v.y : c == 2 ? v.z : v.w;
}
static __device__ __forceinline__ unsigned int packh2(float a, float b) {
  f16_t h0 = (f16_t)a, h1 = (f16_t)b;
  return (unsigned int)__builtin_bit_cast(unsigned short, h0)
       | ((unsigned int)__builtin_bit_cast(unsigned short, h1) << 16);
}

// ---------------- convert: x -> 5 shifted f16 images TS; y -> 5 shifted f16 images YS ----------------
// TS_s[cg][r][j] = x[cg][r][j+s] (0 outside).  YS_v[nb][r][j] = y[nb][r][j+2-v] (0 outside).
__global__ __launch_bounds__(256) void convert_kernel(const float* __restrict__ xs,
                                                      const float* __restrict__ ys,
                                                      unsigned int* __restrict__ TS32,
                                                      unsigned int* __restrict__ YS32) {
  const int PER = 256 * 96 * 48;             // 1,179,648 uints per x-shift buffer
  const int TSTOT = 5 * PER;                 // 5,898,240
  int idx = blockIdx.x * 256 + threadIdx.x;
  if (idx < TSTOT) {
    int s = idx / PER;
    int rr = idx - s * PER;
    int p = rr % 48; int t = rr / 48;
    int r = t % 96;  int cg = t / 96;
    const float* row = xs + (size_t)cg * HWSZ + r * 96;
    int j0 = 2 * p, j1 = j0 + 1;
    float f0 = (j0 + s < 96) ? row[j0 + s] : 0.f;
    float f1 = (j1 + s < 96) ? row[j1 + s] : 0.f;
    TS32[idx] = packh2(f0, f1);
  } else {
    int i2 = idx - TSTOT;
    if (i2 >= 5 * 16 * 96 * 48) return;      // 368,640
    int v  = i2 / 73728;                     // 16*96*48
    int r3 = i2 % 73728;
    int nb = r3 / 4608;                      // 96*48
    int r4 = r3 % 4608;
    int r = r4 / 48, p = r4 % 48;
    const float* row = ys + (size_t)nb * HWSZ + r * 96;
    int c0 = 2 * p + 2 - v, c1 = c0 + 1;
    float f0 = (c0 >= 0 && c0 < 96) ? row[c0] : 0.f;
    float f1 = (c1 >= 0 && c1 < 96) ? row[c1] : 0.f;
    YS32[i2] = packh2(f0, f1);
  }
}

// ---------------- merged partial kernel ----------------
// bid < 240: corr band (round-10 proven path).
// bid >= 240 (48 blocks): xty via MFMA — NO register ring (rule #20: runtime
// array index -> scratch). Direct fragA reads with runtime ADDRESSES only;
// all register-array subscripts are literals.
__global__ __launch_bounds__(256, 1) void partial_kernel(const unsigned short* __restrict__ TS,
                                                         const unsigned short* __restrict__ YS,
                                                         float* __restrict__ corrPart,
                                                         float* __restrict__ xtyPart) {
  __shared__ __align__(16) unsigned char lds[24 * SLOTB];   // 159744 B
  int bid = blockIdx.x;
  int tid = threadIdx.x, wid = tid >> 6, lane = tid & 63;
  int l5 = lane >> 5, l31 = lane & 31;

  if (bid < 240) {
    // ================= corr band (round-10 verbatim) =================
    int n = bid & 3;
    int rest = bid >> 2;
    int sv = rest % 5;
    int kc = rest / 5;
    int r0 = kc * RB;
    int mt = wid >> 1, nt = wid & 1;
    const char* Abase = (const char*)TS + (size_t)n * TIMGB;
    const char* Bbase = (const char*)TS + (size_t)sv * TSB + (size_t)n * TIMGB;
    f32x16_t acc[9] = {};

    for (int kh = 0; kh < 2; ++kh) {
      if (kh) __syncthreads();
      for (int bb = 0; bb < 3; ++bb) {
        uint4 tmp[12];
#pragma unroll
        for (int i = 0; i < 12; ++i) {
          int q = (bb * 12 + i) * 256 + tid;
          int slot = q / 384;
          int rem = q - slot * 384;
          int ch = rem / 6, sub = rem - ch * 6;
          bool isA = slot < 16;
          int row = isA ? (r0 - 4 + slot) : (r0 + slot - 16);
          uint4 v = make_uint4(0u, 0u, 0u, 0u);
          if (row >= 0 && row < 96) {
            const char* src = (isA ? Abase : Bbase)
                            + (size_t)ch * TCHB + (size_t)row * TROWB + kh * 96 + sub * 16;
            v = *(const uint4*)src;
          }
          tmp[i] = v;
        }
#pragma unroll
        for (int i = 0; i < 12; ++i) {
          int q = (bb * 12 + i) * 256 + tid;
          int slot = q / 384;
          int rem = q - slot * 384;
          int ch = rem / 6, sub = rem - ch * 6;
          char* dst = (char*)lds + slot * SLOTB + ch * CSTR + sub * 16;
          *(uint2*)dst = make_uint2(tmp[i].x, tmp[i].y);
          *(uint2*)(dst + 8) = make_uint2(tmp[i].z, tmp[i].w);
        }
      }
      __syncthreads();

      int ca = mt * 32 + l31, cb = nt * 32 + l31;
#pragma unroll
      for (int ktl = 0; ktl < 3; ++ktl) {
        int ko = ktl * 32 + l5 * 16;
        auto frag = [&](int slot, int ch) -> f16x8_t {
          const char* p = (const char*)lds + slot * SLOTB + ch * CSTR + ko;
          uint2 lo = *(const uint2*)p;
          uint2 hi = *(const uint2*)(p + 8);
          uint4 u = make_uint4(lo.x, lo.y, hi.x, hi.y);
          return __builtin_bit_cast(f16x8_t, u);
        };
        f16x8_t ring[9];
#pragma unroll
        for (int t = 0; t < 9; ++t) ring[t] = frag(t, ca);
#pragma unroll
        for (int r = 0; r < 8; ++r) {
          f16x8_t b = frag(16 + r, cb);
#pragma unroll
          for (int du = 0; du < 9; ++du) {
            acc[du] = __builtin_amdgcn_mfma_f32_32x32x16_f16(
                ring[(r + 8 - du) % 9], b, acc[du], 0, 0, 0);   // static indices
          }
          if (r < 7) ring[r % 9] = frag(r + 9, ca);
        }
      }
    }
#pragma unroll
    for (int du = 0; du < 9; ++du) {
      float* outp = corrPart + (((size_t)(sv * 9 + du) * SKC + kc) * 4 + n) * 4096;
#pragma unroll
      for (int rg = 0; rg < 16; ++rg) {
        int m  = mt * 32 + (rg & 3) + 8 * (rg >> 2) + 4 * l5;
        int nn = nt * 32 + l31;
        outp[m * 64 + nn] = acc[du][rg];
      }
    }
    return;
  }

  // ================= xty MFMA (ring-free, scratch-safe) =================
  int id = bid - 240;                 // 48 = 4n x 12kc
  int n = id & 3, kc = id >> 2;
  int r0 = kc * RB;
  int mt = wid & 1, rh = wid >> 1;    // mt: A row-half; rh: B row-half (j 0..3 / 4..7)
  const char* Ab = (const char*)TS + (size_t)n * TIMGB;   // x shift 0
  const char* Yb = (const char*)YS;
  f32x16_t acc[5] = {};

  for (int kh = 0; kh < 2; ++kh) {
    if (kh) __syncthreads();
    for (int bb = 0; bb < 2; ++bb) {
      uint4 tmp[12];
#pragma unroll
      for (int i = 0; i < 12; ++i) {
        int q = (bb * 12 + i) * 256 + tid;   // < 6144
        uint4 val = make_uint4(0u, 0u, 0u, 0u);
        if (q < 4608) {                      // A: 12 slots x 64ch x 6
          int slot = q / 384, rem = q % 384, ch = rem / 6, sub = rem % 6;
          int grow = r0 - 2 + slot;
          if (grow >= 0 && grow < 96)
            val = *(const uint4*)(Ab + (size_t)ch * TCHB + (size_t)grow * TROWB + kh * 96 + sub * 16);
        } else if (q < 5568) {               // B real: 8 slots x 20col x 6
          int qq = q - 4608;
          int j = qq / 120, rem = qq % 120, col = rem / 6, sub = rem % 6;
          int b = col / 5, v = col % 5;
          int grow = r0 + j;
          val = *(const uint4*)(Yb + ((size_t)(v * 16 + n * 4 + b) * 96 + grow) * 192 + kh * 96 + sub * 16);
        }                                    // 5568..6143: zero pad cols 20..31
        tmp[i] = val;
      }
#pragma unroll
      for (int i = 0; i < 12; ++i) {
        int q = (bb * 12 + i) * 256 + tid;
        char* dst;
        if (q < 4608) {
          int slot = q / 384, rem = q % 384, ch = rem / 6, sub = rem % 6;
          dst = (char*)lds + XAOFF + slot * SLOTB + ch * CSTR + sub * 16;
        } else {
          int j, col, sub;
          if (q < 5568) { int qq = q - 4608; j = qq / 120; int rem = qq % 120; col = rem / 6; sub = rem % 6; }
          else          { int q2 = q - 5568; j = q2 / 72;  int rem = q2 % 72;  col = 20 + rem / 6; sub = rem % 6; }
          dst = (char*)lds + XBOFF + j * XBSLOT + col * CSTR + sub * 16;
        }
        *(uint2*)dst = make_uint2(tmp[i].x, tmp[i].y);
        *(uint2*)(dst + 8) = make_uint2(tmp[i].z, tmp[i].w);
      }
    }
    __syncthreads();

    int ca = mt * 32 + l31;
    int jb = rh * 4;                         // runtime, enters addresses only
#pragma unroll
    for (int ktl = 0; ktl < 3; ++ktl) {
      int ko = ktl * 32 + l5 * 16;
      auto fragA = [&](int slot) -> f16x8_t {
        const char* p = (const char*)lds + XAOFF + slot * SLOTB + ca * CSTR + ko;
        uint2 lo = *(const uint2*)p; uint2 hi = *(const uint2*)(p + 8);
        return __builtin_bit_cast(f16x8_t, make_uint4(lo.x, lo.y, hi.x, hi.y));
      };
      auto fragB = [&](int j) -> f16x8_t {
        const char* p = (const char*)lds + XBOFF + j * XBSLOT + l31 * CSTR + ko;
        uint2 lo = *(const uint2*)p; uint2 hi = *(const uint2*)(p + 8);
        return __builtin_bit_cast(f16x8_t, make_uint4(lo.x, lo.y, hi.x, hi.y));
      };
#pragma unroll
      for (int jj = 0; jj < 4; ++jj) {
        f16x8_t b  = fragB(jb + jj);
        f16x8_t a0 = fragA(jb + jj + 0);     // named scalars, literal acc indices
        f16x8_t a1 = fragA(jb + jj + 1);
        f16x8_t a2 = fragA(jb + jj + 2);
        f16x8_t a3 = fragA(jb + jj + 3);
        f16x8_t a4 = fragA(jb + jj + 4);
        acc[0] = __builtin_amdgcn_mfma_f32_32x32x16_f16(a0, b, acc[0], 0, 0, 0);
        acc[1] = __builtin_amdgcn_mfma_f32_32x32x16_f16(a1, b, acc[1], 0, 0, 0);
        acc[2] = __builtin_amdgcn_mfma_f32_32x32x16_f16(a2, b, acc[2], 0, 0, 0);
        acc[3] = __builtin_amdgcn_mfma_f32_32x32x16_f16(a3, b, acc[3], 0, 0, 0);
        acc[4] = __builtin_amdgcn_mfma_f32_32x32x16_f16(a4, b, acc[4], 0, 0, 0);
      }
    }
  }

  // cross-wave (rh) reduce via LDS scratch, then write xtyPart[n][kc][u][64][32]
  __syncthreads();
  float* scr = (float*)lds;
#pragma unroll
  for (int u = 0; u < 5; ++u)
#pragma unroll
    for (int rg = 0; rg < 16; ++rg) {
      int m = mt * 32 + (rg & 3) + 8 * (rg >> 2) + 4 * l5;
      scr[rh * 10240 + u * 2048 + m * 32 + l31] = acc[u][rg];
    }
  __syncthreads();
  float* outp = xtyPart + (size_t)(n * SKC + kc) * 5 * 2048;
  for (int e = tid; e < 10240; e += 256)
    outp[e] = scr[e] + scr[10240 + e];
}

// ---------------- fused: corr reduce (0..163) + P build (164..263) ----------------
__global__ __launch_bounds__(256) void reduce_kernel(const float* __restrict__ corrPart,
                                                     float* __restrict__ corrP,
                                                     const float* __restrict__ xtyPart,
                                                     const float* __restrict__ dd,
                                                     const float* __restrict__ alpha,
                                                     const float* __restrict__ reg,
                                                     float* __restrict__ P) {
  int bid0 = blockIdx.x;
  if (bid0 < 164) {
    int n = bid0 / 41, p = bid0 % 41;
    int du, dv;
    if (p < 36) { du = p % 9; dv = 5 + p / 9; }
    else        { du = p - 36; dv = 4; }
    int t = (p < 36) ? (9 + p) : (p - 36);
    int o1 = du * 9 + dv, o2 = (8 - du) * 9 + (8 - dv);
    bool mir = !(du == 4 && dv == 4);
    for (int e = threadIdx.x; e < 4096; e += 256) {
      float s = 0.f;
#pragma unroll
      for (int kc = 0; kc < SKC; ++kc)
        s += corrPart[(((size_t)t * SKC + kc) * 4 + n) * 4096 + e];
      int m = e >> 6, nn = e & 63;
      corrP[((size_t)(n * 64 + m) * 64 + nn) * CORR_RS + o1] = s;
      if (mir) corrP[((size_t)(n * 64 + nn) * 64 + m) * CORR_RS + o2] = s;
    }
    return;
  }
  // P build: idx = ((n*1600 + c*25+u*5+v)*4 + b)
  int idx = (bid0 - 164) * 256 + threadIdx.x;   // < 25600
  int b = idx & 3;
  int row = (idx >> 2) % KD;
  int n = idx / 6400;
  int c = row / 25;
  int uv = row % 25;
  int u = uv / 5, v = uv % 5;
  float s = 0.f;
#pragma unroll
  for (int kc = 0; kc < SKC; ++kc)
    s += xtyPart[((size_t)(n * SKC + kc) * 5 + u) * 2048 + c * 32 + b * 5 + v];
  float a = alpha[n] * reg[0] * ((float)(HH * WW) / (float)(DS * DS * CIN));
  float dvv = dd[((size_t)(n * COUT + b) * CIN + c) * 25 + uv];
  P[idx] = s + a * dvv;
}

// ---------------- fused CG iteration (proven) ----------------
static __device__ __forceinline__ void allreduce2_f4(float4& a, float4& b,
                                                     float4* redA, float4* redB, int tid) {
#pragma unroll
  for (int off = 1; off < 64; off <<= 1) {
    a.x += __shfl_xor(a.x, off); a.y += __shfl_xor(a.y, off);
    a.z += __shfl_xor(a.z, off); a.w += __shfl_xor(a.w, off);
    b.x += __shfl_xor(b.x, off); b.y += __shfl_xor(b.y, off);
    b.z += __shfl_xor(b.z, off); b.w += __shfl_xor(b.w, off);
  }
  int wid = tid >> 6;
  if ((tid & 63) == 0) { redA[wid] = a; redB[wid] = b; }
  __syncthreads();
  float4 sa = f4add(f4add(redA[0], redA[1]), f4add(redA[2], redA[3]));
  float4 sb = f4add(f4add(redB[0], redB[1]), f4add(redB[2], redB[3]));
  __syncthreads();
  a = sa; b = sb;
}

__global__ __launch_bounds__(256) void cg_iter_kernel(
    const float* __restrict__ corrP, const float* __restrict__ P,
    const float* __restrict__ Rin, float* __restrict__ Rout,
    const float* __restrict__ Win, float* __restrict__ Wout,
    const float* __restrict__ PFin, float* __restrict__ PFout,
    float* __restrict__ X,
    const float* __restrict__ ralpha, const float* __restrict__ rreg,
    int first) {
  __shared__ float4 pS[KD];
  __shared__ float4 redA[4], redB[4];
  __shared__ float redW[4][25][4];

  int b = blockIdx.x;
  int n = b >> 6, c1 = b & 63;
  int tid = threadIdx.x;

  const float4* Rin4 = (const float4*)Rin + (size_t)n * KD;
  const float4* Win4 = (const float4*)Win + (size_t)n * KD;
  const float4* PFin4 = (const float4*)PFin + (size_t)n * KD;
  const float4* P4 = (const float4*)P + (size_t)n * KD;
  float4* Rout4 = (float4*)Rout + (size_t)n * KD;
  float4* PFout4 = (float4*)PFout + (size_t)n * KD;
  float4* X4 = (float4*)X + (size_t)n * KD;

  const float4 zero4 = make_float4(0.f, 0.f, 0.f, 0.f);
  float4 rv[7], wv[7], pv[7];
#pragma unroll
  for (int t = 0; t < 7; ++t) {
    int idx = tid + 256 * t;
    bool ok = idx < KD;
    if (first) {
      rv[t] = ok ? P4[idx] : zero4;
      wv[t] = zero4; pv[t] = zero4;
    } else {
      rv[t] = ok ? Rin4[idx] : zero4;
      wv[t] = ok ? Win4[idx] : zero4;
      pv[t] = ok ? PFin4[idx] : zero4;
    }
  }
  float4 rho_prev = zero4, pAp = zero4;
#pragma unroll
  for (int t = 0; t < 7; ++t) {
    rho_prev = f4fma(rv[t], rv[t], rho_prev);
    pAp = f4fma(pv[t], wv[t], pAp);
  }
  allreduce2_f4(rho_prev, pAp, redA, redB, tid);

  float4 av = first ? zero4 : f4div(rho_prev, pAp);

  float4 rho_k = zero4;
#pragma unroll
  for (int t = 0; t < 7; ++t) {
    rv[t] = f4sub(rv[t], f4mul(av, wv[t]));
    rho_k = f4fma(rv[t], rv[t], rho_k);
  }
  int lo = c1 * 25;
#pragma unroll
  for (int t = 0; t < 7; ++t) {
    int idx = tid + 256 * t;
    if (idx >= lo && idx < lo + 25) {
      if (first) X4[idx] = zero4;
      else X4[idx] = f4fma(av, pv[t], X4[idx]);
    }
  }
  float4 dummy = zero4;
  allreduce2_f4(rho_k, dummy, redA, redB, tid);

  float4 bv = first ? zero4 : f4div(rho_k, rho_prev);

#pragma unroll
  for (int t = 0; t < 7; ++t) {
    int idx = tid + 256 * t;
    if (idx < KD) {
      float4 pnew = f4fma(bv, pv[t], rv[t]);
      pS[idx] = pnew;
      if (idx >= lo && idx < lo + 25) {
        PFout4[idx] = pnew;
        Rout4[idx] = rv[t];
      }
    }
  }
  __syncthreads();

  int c2 = tid >> 2, col = tid & 3;
  const float4* crow4 = (const float4*)(corrP + (((size_t)(n * 64 + c1)) * 64 + c2) * CORR_RS);
  float creg[81];
#pragma unroll
  for (int t4 = 0; t4 < 20; ++t4) *(float4*)&creg[4 * t4] = crow4[t4];
  creg[80] = ((const float*)crow4)[80];

  float a25[25];
#pragma unroll
  for (int i = 0; i < 25; ++i) a25[i] = 0.f;
  const float* pSf = (const float*)pS;
#pragma unroll
  for (int j = 0; j < 25; ++j) {
    float pvv = pSf[(c2 * 25 + j) * 4 + col];
#pragma unroll
    for (int i = 0; i < 25; ++i) {
      const int i1 = i / 5, i2 = i % 5, j1 = j / 5, j2 = j % 5;
      a25[i] += creg[(j1 - i1 + 4) * 9 + (j2 - i2 + 4)] * pvv;
    }
  }
#pragma unroll
  for (int i = 0; i < 25; ++i) {
    float v = a25[i];
    v += __shfl_xor(v, 4); v += __shfl_xor(v, 8);
    v += __shfl_xor(v, 16); v += __shfl_xor(v, 32);
    a25[i] = v;
  }
  int wid = tid >> 6;
  if ((tid & 63) < 4) {
#pragma unroll
    for (int i = 0; i < 25; ++i) redW[wid][i][col] = a25[i];
  }
  __syncthreads();
  if (tid < 100) {
    int i = tid >> 2, cc = tid & 3;
    float wval = redW[0][i][cc] + redW[1][i][cc] + redW[2][i][cc] + redW[3][i][cc];
    float aa = ralpha[n] * rreg[0] * ((float)(HH * WW) / (float)(DS * DS * CIN));
    int row = lo + i;
    wval = fmaf(aa, pSf[row * 4 + cc], wval);
    Wout[((size_t)n * KD + row) * 4 + cc] = wval;
  }
}

// ---------------- finalize ----------------
__global__ __launch_bounds__(256) void cg_final_kernel(
    const float* __restrict__ Rin, const float* __restrict__ Win,
    const float* __restrict__ PFin, const float* __restrict__ X,
    float* __restrict__ out) {
  __shared__ float4 redA[4], redB[4];
  int b = blockIdx.x;
  int n = b >> 6, c1 = b & 63;
  int tid = threadIdx.x;

  const float4* Rin4 = (const float4*)Rin + (size_t)n * KD;
  const float4* Win4 = (const float4*)Win + (size_t)n * KD;
  const float4* PFin4 = (const float4*)PFin + (size_t)n * KD;
  const float4 zero4 = make_float4(0.f, 0.f, 0.f, 0.f);

  float4 rho = zero4, pAp = zero4;
#pragma unroll
  for (int t = 0; t < 7; ++t) {
    int idx = tid + 256 * t;
    if (idx < KD) {
      float4 r = Rin4[idx], w = Win4[idx], p = PFin4[idx];
      rho = f4fma(r, r, rho);
      pAp = f4fma(p, w, pAp);
    }
  }
  allreduce2_f4(rho, pAp, redA, redB, tid);
  float4 av = f4div(rho, pAp);

  if (tid < 100) {
    int i = tid >> 2, cc = tid & 3;
    int row = c1 * 25 + i;
    float a_cc = f4sel(av, cc);
    float xv = X[((size_t)n * KD + row) * 4 + cc] + a_cc * PFin[((size_t)n * KD + row) * 4 + cc];
    out[((size_t)(n * 4 + cc) * 64 + c1) * 25 + i] = xv;
  }
}

extern "C" void kernel_launch(void* const* d_in, const int* in_sizes, int n_in,
                              void* d_out, int out_size, void* d_ws, size_t ws_size,
                              hipStream_t stream) {
  (void)in_sizes; (void)n_in; (void)out_size; (void)ws_size;
  const float* xs    = (const float*)d_in[0];   // [4,1,64,96,96]
  const float* dd    = (const float*)d_in[1];   // [4,4,64,5,5]
  const float* ys    = (const float*)d_in[2];   // [4,4,1,96,96]
  const float* alpha = (const float*)d_in[3];   // [4]
  const float* reg   = (const float*)d_in[4];   // [1]
  float* out = (float*)d_out;
  float* ws  = (float*)d_ws;

  const size_t TS_FLOATS = 5898240;                        // 5 x 256 x 96 x 48 uints
  const size_t YS_FLOATS = 368640;                         // 5 x 16 x 96 x 48 uints
  const size_t SZ_CPART = (size_t)45 * SKC * 4 * 4096;     // 8,847,360
  const size_t SZ_XPART = (size_t)4 * SKC * 5 * 2048;      // 491,520
  const size_t SZ_V = (size_t)NS * KD * COUT;              // 25,600

  unsigned short* TS = (unsigned short*)ws;                // dead after partial
  unsigned short* YS = (unsigned short*)(ws + TS_FLOATS);  // dead after partial
  float* corrP = ws;                                       // overlays dead TS
  float* corrPart = ws + TS_FLOATS + YS_FLOATS;
  float* xtyPart = corrPart + SZ_CPART;
  float* P   = xtyPart + SZ_XPART;
  float* X   = P + SZ_V;
  float* R0  = X + SZ_V;
  float* R1  = R0 + SZ_V;
  float* W0  = R1 + SZ_V;
  float* W1  = W0 + SZ_V;
  float* PF0 = W1 + SZ_V;
  float* PF1 = PF0 + SZ_V;
  float* Rb[2] = {R0, R1};
  float* Wb[2] = {W0, W1};
  float* Pb[2] = {PF0, PF1};

  convert_kernel<<<24480, 256, 0, stream>>>(xs, ys, (unsigned int*)TS, (unsigned int*)YS);
  partial_kernel<<<288, 256, 0, stream>>>(TS, YS, corrPart, xtyPart);
  reduce_kernel<<<264, 256, 0, stream>>>(corrPart, corrP, xtyPart, dd, alpha, reg, P);
  for (int k = 0; k < ITER; ++k) {
    cg_iter_kernel<<<NS * CIN, 256, 0, stream>>>(
        corrP, P,
        Rb[k & 1], Rb[(k + 1) & 1],
        Wb[k & 1], Wb[(k + 1) & 1],
        Pb[k & 1], Pb[(k + 1) & 1],
        X, alpha, reg, k == 0 ? 1 : 0);
  }
  cg_final_kernel<<<NS * CIN, 256, 0, stream>>>(Rb[ITER & 1], Wb[ITER & 1], Pb[ITER & 1], X, out);
}

// Round 13
// 130.188 us; speedup vs baseline: 5.0138x; 1.0718x over previous
//
#include <hip/hip_runtime.h>

// Problem constants
#define NS   4
#define CIN  64
#define COUT 4
#define HH   96
#define WW   96
#define HWSZ 9216
#define DS   5
#define KD   1600
#define ITER 6

// Tight f16 image geometry (5 shift buffers, 96 f16 per row)
#define TROWB 192                   // bytes per row (96 f16)
#define TCHB  (96*TROWB)            // per-channel bytes (18432)
#define TIMGB ((size_t)64*TCHB)     // per-sample bytes
#define TSB   ((size_t)256*TCHB)    // per-shift-buffer bytes
#define CORR_RS 84                  // corr row stride in floats

#define SKC  12                     // kc chunks (8 B-rows each)
#define RB   8

// LDS band geometry (corr path): 24 row-slots
#define CSTR  104                   // channel stride bytes (26 dwords -> 2-way banks, free)
#define SLOTB (64*CSTR)             // 6656; 24*6656 = 159744

// xty LDS geometry: A = 12 slots x 64ch x 104B (79872); B at 79872: 8 slots x 32col x 104B
#define XAOFF 0
#define XBOFF 79872
#define XBSLOT (32*CSTR)            // 3328

typedef _Float16 f16_t;
typedef _Float16 f16x8_t __attribute__((ext_vector_type(8)));
typedef float    f32x16_t __attribute__((ext_vector_type(16)));

static __device__ __forceinline__ float4 f4add(float4 a, float4 b) {
  return make_float4(a.x + b.x, a.y + b.y, a.z + b.z, a.w + b.w);
}
static __device__ __forceinline__ float4 f4sub(float4 a, float4 b) {
  return make_float4(a.x - b.x, a.y - b.y, a.z - b.z, a.w - b.w);
}
static __device__ __forceinline__ float4 f4mul(float4 a, float4 b) {
  return make_float4(a.x * b.x, a.y * b.y, a.z * b.z, a.w * b.w);
}
static __device__ __forceinline__ float4 f4div(float4 a, float4 b) {
  return make_float4(a.x / b.x, a.y / b.y, a.z / b.z, a.w / b.w);
}
static __device__ __forceinline__ float4 f4fma(float4 a, float4 b, float4 c) {
  return make_float4(fmaf(a.x, b.x, c.x), fmaf(a.y, b.y, c.y),
                     fmaf(a.z, b.z, c.z), fmaf(a.w, b.w, c.w));
}
static __device__ __forceinline__ float f4sel(float4 v, int c) {
  return c == 0 ? v.x : c == 1 ? v.y : c == 2 ? v.z : v.w;
}
static __device__ __forceinline__ unsigned int packh2(float a, float b) {
  f16_t h0 = (f16_t)a, h1 = (f16_t)b;
  return (unsigned int)__builtin_bit_cast(unsigned short, h0)
       | ((unsigned int)__builtin_bit_cast(unsigned short, h1) << 16);
}

// ---------------- convert: x -> 5 shifted f16 images TS; y -> 5 shifted f16 images YS ----------------
// TS_s[cg][r][j] = x[cg][r][j+s] (0 outside).  YS_v[nb][r][j] = y[nb][r][j+2-v] (0 outside).
__global__ __launch_bounds__(256) void convert_kernel(const float* __restrict__ xs,
                                                      const float* __restrict__ ys,
                                                      unsigned int* __restrict__ TS32,
                                                      unsigned int* __restrict__ YS32) {
  const int PER = 256 * 96 * 48;             // 1,179,648 uints per x-shift buffer
  const int TSTOT = 5 * PER;                 // 5,898,240
  int idx = blockIdx.x * 256 + threadIdx.x;
  if (idx < TSTOT) {
    int s = idx / PER;
    int rr = idx - s * PER;
    int p = rr % 48; int t = rr / 48;
    int r = t % 96;  int cg = t / 96;
    const float* row = xs + (size_t)cg * HWSZ + r * 96;
    int j0 = 2 * p, j1 = j0 + 1;
    float f0 = (j0 + s < 96) ? row[j0 + s] : 0.f;
    float f1 = (j1 + s < 96) ? row[j1 + s] : 0.f;
    TS32[idx] = packh2(f0, f1);
  } else {
    int i2 = idx - TSTOT;
    if (i2 >= 5 * 16 * 96 * 48) return;      // 368,640
    int v  = i2 / 73728;                     // 16*96*48
    int r3 = i2 % 73728;
    int nb = r3 / 4608;                      // 96*48
    int r4 = r3 % 4608;
    int r = r4 / 48, p = r4 % 48;
    const float* row = ys + (size_t)nb * HWSZ + r * 96;
    int c0 = 2 * p + 2 - v, c1 = c0 + 1;
    float f0 = (c0 >= 0 && c0 < 96) ? row[c0] : 0.f;
    float f1 = (c1 >= 0 && c1 < 96) ? row[c1] : 0.f;
    YS32[i2] = packh2(f0, f1);
  }
}

// ---------------- merged partial kernel ----------------
// bid < 240: corr band. bid >= 240 (48 blocks): xty via MFMA (ring-free, rule #20 safe).
__global__ __launch_bounds__(256, 1) void partial_kernel(const unsigned short* __restrict__ TS,
                                                         const unsigned short* __restrict__ YS,
                                                         float* __restrict__ corrPart,
                                                         float* __restrict__ xtyPart) {
  __shared__ __align__(16) unsigned char lds[24 * SLOTB];   // 159744 B
  int bid = blockIdx.x;
  int tid = threadIdx.x, wid = tid >> 6, lane = tid & 63;
  int l5 = lane >> 5, l31 = lane & 31;

  if (bid < 240) {
    // ================= corr band =================
    int n = bid & 3;
    int rest = bid >> 2;
    int sv = rest % 5;
    int kc = rest / 5;
    int r0 = kc * RB;
    int mt = wid >> 1, nt = wid & 1;
    const char* Abase = (const char*)TS + (size_t)n * TIMGB;
    const char* Bbase = (const char*)TS + (size_t)sv * TSB + (size_t)n * TIMGB;
    f32x16_t acc[9] = {};

    for (int kh = 0; kh < 2; ++kh) {
      if (kh) __syncthreads();
      for (int bb = 0; bb < 3; ++bb) {
        uint4 tmp[12];
#pragma unroll
        for (int i = 0; i < 12; ++i) {
          int q = (bb * 12 + i) * 256 + tid;
          int slot = q / 384;
          int rem = q - slot * 384;
          int ch = rem / 6, sub = rem - ch * 6;
          bool isA = slot < 16;
          int row = isA ? (r0 - 4 + slot) : (r0 + slot - 16);
          uint4 v = make_uint4(0u, 0u, 0u, 0u);
          if (row >= 0 && row < 96) {
            const char* src = (isA ? Abase : Bbase)
                            + (size_t)ch * TCHB + (size_t)row * TROWB + kh * 96 + sub * 16;
            v = *(const uint4*)src;
          }
          tmp[i] = v;
        }
#pragma unroll
        for (int i = 0; i < 12; ++i) {
          int q = (bb * 12 + i) * 256 + tid;
          int slot = q / 384;
          int rem = q - slot * 384;
          int ch = rem / 6, sub = rem - ch * 6;
          char* dst = (char*)lds + slot * SLOTB + ch * CSTR + sub * 16;
          *(uint2*)dst = make_uint2(tmp[i].x, tmp[i].y);
          *(uint2*)(dst + 8) = make_uint2(tmp[i].z, tmp[i].w);
        }
      }
      __syncthreads();

      int ca = mt * 32 + l31, cb = nt * 32 + l31;
#pragma unroll
      for (int ktl = 0; ktl < 3; ++ktl) {
        int ko = ktl * 32 + l5 * 16;
        auto frag = [&](int slot, int ch) -> f16x8_t {
          const char* p = (const char*)lds + slot * SLOTB + ch * CSTR + ko;
          uint2 lo = *(const uint2*)p;
          uint2 hi = *(const uint2*)(p + 8);
          uint4 u = make_uint4(lo.x, lo.y, hi.x, hi.y);
          return __builtin_bit_cast(f16x8_t, u);
        };
        f16x8_t ring[9];
#pragma unroll
        for (int t = 0; t < 9; ++t) ring[t] = frag(t, ca);
#pragma unroll
        for (int r = 0; r < 8; ++r) {
          f16x8_t b = frag(16 + r, cb);
#pragma unroll
          for (int du = 0; du < 9; ++du) {
            acc[du] = __builtin_amdgcn_mfma_f32_32x32x16_f16(
                ring[(r + 8 - du) % 9], b, acc[du], 0, 0, 0);   // static indices
          }
          if (r < 7) ring[r % 9] = frag(r + 9, ca);
        }
      }
    }
#pragma unroll
    for (int du = 0; du < 9; ++du) {
      float* outp = corrPart + (((size_t)(sv * 9 + du) * SKC + kc) * 4 + n) * 4096;
#pragma unroll
      for (int rg = 0; rg < 16; ++rg) {
        int m  = mt * 32 + (rg & 3) + 8 * (rg >> 2) + 4 * l5;
        int nn = nt * 32 + l31;
        outp[m * 64 + nn] = acc[du][rg];
      }
    }
    return;
  }

  // ================= xty MFMA (ring-free, scratch-safe) =================
  int id = bid - 240;                 // 48 = 4n x 12kc
  int n = id & 3, kc = id >> 2;
  int r0 = kc * RB;
  int mt = wid & 1, rh = wid >> 1;    // mt: A row-half; rh: B row-half (j 0..3 / 4..7)
  const char* Ab = (const char*)TS + (size_t)n * TIMGB;   // x shift 0
  const char* Yb = (const char*)YS;
  f32x16_t acc[5] = {};

  for (int kh = 0; kh < 2; ++kh) {
    if (kh) __syncthreads();
    for (int bb = 0; bb < 2; ++bb) {
      uint4 tmp[12];
#pragma unroll
      for (int i = 0; i < 12; ++i) {
        int q = (bb * 12 + i) * 256 + tid;   // < 6144
        uint4 val = make_uint4(0u, 0u, 0u, 0u);
        if (q < 4608) {                      // A: 12 slots x 64ch x 6
          int slot = q / 384, rem = q % 384, ch = rem / 6, sub = rem % 6;
          int grow = r0 - 2 + slot;
          if (grow >= 0 && grow < 96)
            val = *(const uint4*)(Ab + (size_t)ch * TCHB + (size_t)grow * TROWB + kh * 96 + sub * 16);
        } else if (q < 5568) {               // B real: 8 slots x 20col x 6
          int qq = q - 4608;
          int j = qq / 120, rem = qq % 120, col = rem / 6, sub = rem % 6;
          int b = col / 5, v = col % 5;
          int grow = r0 + j;
          val = *(const uint4*)(Yb + ((size_t)(v * 16 + n * 4 + b) * 96 + grow) * 192 + kh * 96 + sub * 16);
        }                                    // 5568..6143: zero pad cols 20..31
        tmp[i] = val;
      }
#pragma unroll
      for (int i = 0; i < 12; ++i) {
        int q = (bb * 12 + i) * 256 + tid;
        char* dst;
        if (q < 4608) {
          int slot = q / 384, rem = q % 384, ch = rem / 6, sub = rem % 6;
          dst = (char*)lds + XAOFF + slot * SLOTB + ch * CSTR + sub * 16;
        } else {
          int j, col, sub;
          if (q < 5568) { int qq = q - 4608; j = qq / 120; int rem = qq % 120; col = rem / 6; sub = rem % 6; }
          else          { int q2 = q - 5568; j = q2 / 72;  int rem = q2 % 72;  col = 20 + rem / 6; sub = rem % 6; }
          dst = (char*)lds + XBOFF + j * XBSLOT + col * CSTR + sub * 16;
        }
        *(uint2*)dst = make_uint2(tmp[i].x, tmp[i].y);
        *(uint2*)(dst + 8) = make_uint2(tmp[i].z, tmp[i].w);
      }
    }
    __syncthreads();

    int ca = mt * 32 + l31;
    int jb = rh * 4;                         // runtime, enters addresses only
#pragma unroll
    for (int ktl = 0; ktl < 3; ++ktl) {
      int ko = ktl * 32 + l5 * 16;
      auto fragA = [&](int slot) -> f16x8_t {
        const char* p = (const char*)lds + XAOFF + slot * SLOTB + ca * CSTR + ko;
        uint2 lo = *(const uint2*)p; uint2 hi = *(const uint2*)(p + 8);
        return __builtin_bit_cast(f16x8_t, make_uint4(lo.x, lo.y, hi.x, hi.y));
      };
      auto fragB = [&](int j) -> f16x8_t {
        const char* p = (const char*)lds + XBOFF + j * XBSLOT + l31 * CSTR + ko;
        uint2 lo = *(const uint2*)p; uint2 hi = *(const uint2*)(p + 8);
        return __builtin_bit_cast(f16x8_t, make_uint4(lo.x, lo.y, hi.x, hi.y));
      };
#pragma unroll
      for (int jj = 0; jj < 4; ++jj) {
        f16x8_t b  = fragB(jb + jj);
        f16x8_t a0 = fragA(jb + jj + 0);     // named scalars, literal acc indices
        f16x8_t a1 = fragA(jb + jj + 1);
        f16x8_t a2 = fragA(jb + jj + 2);
        f16x8_t a3 = fragA(jb + jj + 3);
        f16x8_t a4 = fragA(jb + jj + 4);
        acc[0] = __builtin_amdgcn_mfma_f32_32x32x16_f16(a0, b, acc[0], 0, 0, 0);
        acc[1] = __builtin_amdgcn_mfma_f32_32x32x16_f16(a1, b, acc[1], 0, 0, 0);
        acc[2] = __builtin_amdgcn_mfma_f32_32x32x16_f16(a2, b, acc[2], 0, 0, 0);
        acc[3] = __builtin_amdgcn_mfma_f32_32x32x16_f16(a3, b, acc[3], 0, 0, 0);
        acc[4] = __builtin_amdgcn_mfma_f32_32x32x16_f16(a4, b, acc[4], 0, 0, 0);
      }
    }
  }

  // cross-wave (rh) reduce via LDS scratch, then write xtyPart[n][kc][u][64][32]
  __syncthreads();
  float* scr = (float*)lds;
#pragma unroll
  for (int u = 0; u < 5; ++u)
#pragma unroll
    for (int rg = 0; rg < 16; ++rg) {
      int m = mt * 32 + (rg & 3) + 8 * (rg >> 2) + 4 * l5;
      scr[rh * 10240 + u * 2048 + m * 32 + l31] = acc[u][rg];
    }
  __syncthreads();
  float* outp = xtyPart + (size_t)(n * SKC + kc) * 5 * 2048;
  for (int e = tid; e < 10240; e += 256)
    outp[e] = scr[e] + scr[10240 + e];
}

// ---------------- fused: corr reduce (0..163) + P build (164..263) ----------------
__global__ __launch_bounds__(256) void reduce_kernel(const float* __restrict__ corrPart,
                                                     float* __restrict__ corrP,
                                                     const float* __restrict__ xtyPart,
                                                     const float* __restrict__ dd,
                                                     const float* __restrict__ alpha,
                                                     const float* __restrict__ reg,
                                                     float* __restrict__ P) {
  int bid0 = blockIdx.x;
  if (bid0 < 164) {
    int n = bid0 / 41, p = bid0 % 41;
    int du, dv;
    if (p < 36) { du = p % 9; dv = 5 + p / 9; }
    else        { du = p - 36; dv = 4; }
    int t = (p < 36) ? (9 + p) : (p - 36);
    int o1 = du * 9 + dv, o2 = (8 - du) * 9 + (8 - dv);
    bool mir = !(du == 4 && dv == 4);
    for (int e = threadIdx.x; e < 4096; e += 256) {
      float s = 0.f;
#pragma unroll
      for (int kc = 0; kc < SKC; ++kc)
        s += corrPart[(((size_t)t * SKC + kc) * 4 + n) * 4096 + e];
      int m = e >> 6, nn = e & 63;
      corrP[((size_t)(n * 64 + m) * 64 + nn) * CORR_RS + o1] = s;
      if (mir) corrP[((size_t)(n * 64 + nn) * 64 + m) * CORR_RS + o2] = s;
    }
    return;
  }
  // P build: idx = ((n*1600 + c*25+u*5+v)*4 + b)
  int idx = (bid0 - 164) * 256 + threadIdx.x;   // < 25600
  int b = idx & 3;
  int row = (idx >> 2) % KD;
  int n = idx / 6400;
  int c = row / 25;
  int uv = row % 25;
  int u = uv / 5, v = uv % 5;
  float s = 0.f;
#pragma unroll
  for (int kc = 0; kc < SKC; ++kc)
    s += xtyPart[((size_t)(n * SKC + kc) * 5 + u) * 2048 + c * 32 + b * 5 + v];
  float a = alpha[n] * reg[0] * ((float)(HH * WW) / (float)(DS * DS * CIN));
  float dvv = dd[((size_t)(n * COUT + b) * CIN + c) * 25 + uv];
  P[idx] = s + a * dvv;
}

// ---------------- CG ----------------
static __device__ __forceinline__ void allreduce2_f4(float4& a, float4& b,
                                                     float4* redA, float4* redB, int tid) {
#pragma unroll
  for (int off = 1; off < 64; off <<= 1) {
    a.x += __shfl_xor(a.x, off); a.y += __shfl_xor(a.y, off);
    a.z += __shfl_xor(a.z, off); a.w += __shfl_xor(a.w, off);
    b.x += __shfl_xor(b.x, off); b.y += __shfl_xor(b.y, off);
    b.z += __shfl_xor(b.z, off); b.w += __shfl_xor(b.w, off);
  }
  int wid = tid >> 6;
  if ((tid & 63) == 0) { redA[wid] = a; redB[wid] = b; }
  __syncthreads();
  float4 sa = f4add(f4add(redA[0], redA[1]), f4add(redA[2], redA[3]));
  float4 sb = f4add(f4add(redB[0], redB[1]), f4add(redB[2], redB[3]));
  __syncthreads();
  a = sa; b = sb;
}

// single-pass allreduce of FOUR float4 quantities (one LDS round, two barriers)
static __device__ __forceinline__ void allreduce4_f4(float4& a, float4& b, float4& c, float4& d,
                                                     float4 (*red)[4], int tid) {
#pragma unroll
  for (int off = 1; off < 64; off <<= 1) {
    a.x += __shfl_xor(a.x, off); a.y += __shfl_xor(a.y, off);
    a.z += __shfl_xor(a.z, off); a.w += __shfl_xor(a.w, off);
    b.x += __shfl_xor(b.x, off); b.y += __shfl_xor(b.y, off);
    b.z += __shfl_xor(b.z, off); b.w += __shfl_xor(b.w, off);
    c.x += __shfl_xor(c.x, off); c.y += __shfl_xor(c.y, off);
    c.z += __shfl_xor(c.z, off); c.w += __shfl_xor(c.w, off);
    d.x += __shfl_xor(d.x, off); d.y += __shfl_xor(d.y, off);
    d.z += __shfl_xor(d.z, off); d.w += __shfl_xor(d.w, off);
  }
  int wid = tid >> 6;
  if ((tid & 63) == 0) { red[wid][0] = a; red[wid][1] = b; red[wid][2] = c; red[wid][3] = d; }
  __syncthreads();
  float4 sa = f4add(f4add(red[0][0], red[1][0]), f4add(red[2][0], red[3][0]));
  float4 sb = f4add(f4add(red[0][1], red[1][1]), f4add(red[2][1], red[3][1]));
  float4 sc = f4add(f4add(red[0][2], red[1][2]), f4add(red[2][2], red[3][2]));
  float4 sd = f4add(f4add(red[0][3], red[1][3]), f4add(red[2][3], red[3][3]));
  __syncthreads();
  a = sa; b = sb; c = sc; d = sd;
}

// One CG step per launch. Single fused allreduce: reduce {|r|^2, p.w, r.w, |w|^2};
// then rho_k = rho - alpha*(2*(r.w) - alpha*|w|^2)  (exact identity |r - alpha w|^2).
__global__ __launch_bounds__(256) void cg_iter_kernel(
    const float* __restrict__ corrP, const float* __restrict__ P,
    const float* __restrict__ Rin, float* __restrict__ Rout,
    const float* __restrict__ Win, float* __restrict__ Wout,
    const float* __restrict__ PFin, float* __restrict__ PFout,
    float* __restrict__ X,
    const float* __restrict__ ralpha, const float* __restrict__ rreg,
    int first) {
  __shared__ float4 pS[KD];
  __shared__ float4 red4[4][4];
  __shared__ float redW[4][25][4];

  int b = blockIdx.x;
  int n = b >> 6, c1 = b & 63;
  int tid = threadIdx.x;

  const float4* Rin4 = (const float4*)Rin + (size_t)n * KD;
  const float4* Win4 = (const float4*)Win + (size_t)n * KD;
  const float4* PFin4 = (const float4*)PFin + (size_t)n * KD;
  const float4* P4 = (const float4*)P + (size_t)n * KD;
  float4* Rout4 = (float4*)Rout + (size_t)n * KD;
  float4* PFout4 = (float4*)PFout + (size_t)n * KD;
  float4* X4 = (float4*)X + (size_t)n * KD;

  const float4 zero4 = make_float4(0.f, 0.f, 0.f, 0.f);
  float4 rv[7], wv[7], pv[7];
#pragma unroll
  for (int t = 0; t < 7; ++t) {
    int idx = tid + 256 * t;
    bool ok = idx < KD;
    if (first) {
      rv[t] = ok ? P4[idx] : zero4;
      wv[t] = zero4; pv[t] = zero4;
    } else {
      rv[t] = ok ? Rin4[idx] : zero4;
      wv[t] = ok ? Win4[idx] : zero4;
      pv[t] = ok ? PFin4[idx] : zero4;
    }
  }
  float4 rho = zero4, pAp = zero4, rw = zero4, ww = zero4;
#pragma unroll
  for (int t = 0; t < 7; ++t) {
    rho = f4fma(rv[t], rv[t], rho);
    pAp = f4fma(pv[t], wv[t], pAp);
    rw  = f4fma(rv[t], wv[t], rw);
    ww  = f4fma(wv[t], wv[t], ww);
  }
  allreduce4_f4(rho, pAp, rw, ww, red4, tid);

  float4 av = first ? zero4 : f4div(rho, pAp);              // alpha_{k-1}
  // rho_k = rho - av*(2*rw - av*ww)   (== |r - av w|^2 exactly)
  float4 two_rw = f4add(rw, rw);
  float4 inner = f4sub(two_rw, f4mul(av, ww));
  float4 rho_k = f4sub(rho, f4mul(av, inner));
  float4 bv = first ? zero4 : f4div(rho_k, rho);

  int lo = c1 * 25;
#pragma unroll
  for (int t = 0; t < 7; ++t) {
    int idx = tid + 256 * t;
    if (idx < KD) {
      rv[t] = f4sub(rv[t], f4mul(av, wv[t]));               // r_k
      float4 pnew = f4fma(bv, pv[t], rv[t]);                // p_k (uses OLD pv)
      if (idx >= lo && idx < lo + 25) {
        if (first) X4[idx] = zero4;
        else X4[idx] = f4fma(av, pv[t], X4[idx]);           // x += alpha * p_old
        PFout4[idx] = pnew;
        Rout4[idx] = rv[t];
      }
      pS[idx] = pnew;
    }
  }
  __syncthreads();

  int c2 = tid >> 2, col = tid & 3;
  const float4* crow4 = (const float4*)(corrP + (((size_t)(n * 64 + c1)) * 64 + c2) * CORR_RS);
  float creg[81];
#pragma unroll
  for (int t4 = 0; t4 < 20; ++t4) *(float4*)&creg[4 * t4] = crow4[t4];
  creg[80] = ((const float*)crow4)[80];

  float a25[25];
#pragma unroll
  for (int i = 0; i < 25; ++i) a25[i] = 0.f;
  const float* pSf = (const float*)pS;
#pragma unroll
  for (int j = 0; j < 25; ++j) {
    float pvv = pSf[(c2 * 25 + j) * 4 + col];
#pragma unroll
    for (int i = 0; i < 25; ++i) {
      const int i1 = i / 5, i2 = i % 5, j1 = j / 5, j2 = j % 5;
      a25[i] += creg[(j1 - i1 + 4) * 9 + (j2 - i2 + 4)] * pvv;
    }
  }
#pragma unroll
  for (int i = 0; i < 25; ++i) {
    float v = a25[i];
    v += __shfl_xor(v, 4); v += __shfl_xor(v, 8);
    v += __shfl_xor(v, 16); v += __shfl_xor(v, 32);
    a25[i] = v;
  }
  int wid = tid >> 6;
  if ((tid & 63) < 4) {
#pragma unroll
    for (int i = 0; i < 25; ++i) redW[wid][i][col] = a25[i];
  }
  __syncthreads();
  if (tid < 100) {
    int i = tid >> 2, cc = tid & 3;
    float wval = redW[0][i][cc] + redW[1][i][cc] + redW[2][i][cc] + redW[3][i][cc];
    float aa = ralpha[n] * rreg[0] * ((float)(HH * WW) / (float)(DS * DS * CIN));
    int row = lo + i;
    wval = fmaf(aa, pSf[row * 4 + cc], wval);
    Wout[((size_t)n * KD + row) * 4 + cc] = wval;
  }
}

// ---------------- finalize ----------------
__global__ __launch_bounds__(256) void cg_final_kernel(
    const float* __restrict__ Rin, const float* __restrict__ Win,
    const float* __restrict__ PFin, const float* __restrict__ X,
    float* __restrict__ out) {
  __shared__ float4 redA[4], redB[4];
  int b = blockIdx.x;
  int n = b >> 6, c1 = b & 63;
  int tid = threadIdx.x;

  const float4* Rin4 = (const float4*)Rin + (size_t)n * KD;
  const float4* Win4 = (const float4*)Win + (size_t)n * KD;
  const float4* PFin4 = (const float4*)PFin + (size_t)n * KD;
  const float4 zero4 = make_float4(0.f, 0.f, 0.f, 0.f);

  float4 rho = zero4, pAp = zero4;
#pragma unroll
  for (int t = 0; t < 7; ++t) {
    int idx = tid + 256 * t;
    if (idx < KD) {
      float4 r = Rin4[idx], w = Win4[idx], p = PFin4[idx];
      rho = f4fma(r, r, rho);
      pAp = f4fma(p, w, pAp);
    }
  }
  allreduce2_f4(rho, pAp, redA, redB, tid);
  float4 av = f4div(rho, pAp);

  if (tid < 100) {
    int i = tid >> 2, cc = tid & 3;
    int row = c1 * 25 + i;
    float a_cc = f4sel(av, cc);
    float xv = X[((size_t)n * KD + row) * 4 + cc] + a_cc * PFin[((size_t)n * KD + row) * 4 + cc];
    out[((size_t)(n * 4 + cc) * 64 + c1) * 25 + i] = xv;
  }
}

extern "C" void kernel_launch(void* const* d_in, const int* in_sizes, int n_in,
                              void* d_out, int out_size, void* d_ws, size_t ws_size,
                              hipStream_t stream) {
  (void)in_sizes; (void)n_in; (void)out_size; (void)ws_size;
  const float* xs    = (const float*)d_in[0];   // [4,1,64,96,96]
  const float* dd    = (const float*)d_in[1];   // [4,4,64,5,5]
  const float* ys    = (const float*)d_in[2];   // [4,4,1,96,96]
  const float* alpha = (const float*)d_in[3];   // [4]
  const float* reg   = (const float*)d_in[4];   // [1]
  float* out = (float*)d_out;
  float* ws  = (float*)d_ws;

  const size_t TS_FLOATS = 5898240;                        // 5 x 256 x 96 x 48 uints
  const size_t YS_FLOATS = 368640;                         // 5 x 16 x 96 x 48 uints
  const size_t SZ_CPART = (size_t)45 * SKC * 4 * 4096;     // 8,847,360
  const size_t SZ_XPART = (size_t)4 * SKC * 5 * 2048;      // 491,520
  const size_t SZ_V = (size_t)NS * KD * COUT;              // 25,600

  unsigned short* TS = (unsigned short*)ws;                // dead after partial
  unsigned short* YS = (unsigned short*)(ws + TS_FLOATS);  // dead after partial
  float* corrP = ws;                                       // overlays dead TS
  float* corrPart = ws + TS_FLOATS + YS_FLOATS;
  float* xtyPart = corrPart + SZ_CPART;
  float* P   = xtyPart + SZ_XPART;
  float* X   = P + SZ_V;
  float* R0  = X + SZ_V;
  float* R1  = R0 + SZ_V;
  float* W0  = R1 + SZ_V;
  float* W1  = W0 + SZ_V;
  float* PF0 = W1 + SZ_V;
  float* PF1 = PF0 + SZ_V;
  float* Rb[2] = {R0, R1};
  float* Wb[2] = {W0, W1};
  float* Pb[2] = {PF0, PF1};

  convert_kernel<<<24480, 256, 0, stream>>>(xs, ys, (unsigned int*)TS, (unsigned int*)YS);
  partial_kernel<<<288, 256, 0, stream>>>(TS, YS, corrPart, xtyPart);
  reduce_kernel<<<264, 256, 0, stream>>>(corrPart, corrP, xtyPart, dd, alpha, reg, P);
  for (int k = 0; k < ITER; ++k) {
    cg_iter_kernel<<<NS * CIN, 256, 0, stream>>>(
        corrP, P,
        Rb[k & 1], Rb[(k + 1) & 1],
        Wb[k & 1], Wb[(k + 1) & 1],
        Pb[k & 1], Pb[(k + 1) & 1],
        X, alpha, reg, k == 0 ? 1 : 0);
  }
  cg_final_kernel<<<NS * CIN, 256, 0, stream>>>(Rb[ITER & 1], Wb[ITER & 1], Pb[ITER & 1], X, out);
}